// Round 2
// baseline (1264.346 us; speedup 1.0000x reference)
//
#include <hip/hip_runtime.h>
#include <hip/hip_bf16.h>
#include <stdint.h>

#define Bb 4
#define Nn 4096
#define Ww 1024
#define Hh 16
#define Aa 64
#define Pp 64
#define Jj 64   // scan chunks per (b,h)
#define Ll 64   // chunk length  (Jj*Ll == Nn)

__device__ __forceinline__ float clamp20(float z){ return fminf(fmaxf(z, -20.0f), 20.0f); }

// ---- value_weight [H][W][A] -> VW2 [W][H*A] ------------------------------
__global__ __launch_bounds__(256) void t_vw(const float* __restrict__ vw, float* __restrict__ vw2){
    int idx = blockIdx.x * 256 + threadIdx.x;          // h*W*A + w*A + a
    int h = idx >> 16, w = (idx >> 6) & (Ww - 1), a = idx & (Aa - 1);
    vw2[(w << 10) + (h << 6) + a] = vw[idx];
}

// ---- output_weight [H][W][A] -> OW2 [H*A][W] -----------------------------
__global__ __launch_bounds__(256) void t_ow(const float* __restrict__ ow, float* __restrict__ ow2){
    int idx = blockIdx.x * 256 + threadIdx.x;          // r*W + w
    int r = idx >> 10, w = idx & (Ww - 1);
    int h = r >> 6, a = r & (Aa - 1);
    ow2[idx] = ow[(h << 16) + (w << 6) + a];
}

// ---- p1[h,n] raw, p2e[h,n] = exp(clip(p2)) -------------------------------
__global__ __launch_bounds__(256) void p_kernel(const float* __restrict__ a1, const float* __restrict__ a2,
                                                const float* __restrict__ b1, const float* __restrict__ b2,
                                                const float* __restrict__ c,
                                                float* __restrict__ p1, float* __restrict__ p2e){
    int idx = blockIdx.x * 256 + threadIdx.x;          // h*N + i
    int h = idx >> 12, i = idx & (Nn - 1);
    float t = (float)i * (1.0f / (float)(Nn - 1));
    float s1 = 0.f, s2 = 0.f;
    for (int p = 0; p < Pp; ++p){
        float av1 = a1[h * Pp + p];
        float av2 = a2[h * Pp + p];
        float bv1 = b1[h * Pp + p];
        float bv2 = b2[h * Pp + p];
        float cv  = c [h * Pp + p];
        s1 += sinf(av1 * t + bv1) * cv;
        s2 += sinf(av2 * t + bv2) * cv;
    }
    p1[idx]  = s1;
    p2e[idx] = expf(clamp20(s2));
}

// ---- cross_e/diag_e/extra_e [B][H][N]  (one wave per (b,n) row) ----------
__global__ __launch_bounds__(64) void proj_kernel(const float* __restrict__ x,
    const float* __restrict__ k1, const float* __restrict__ k2, const float* __restrict__ k3,
    const float* __restrict__ p1,
    float* __restrict__ cross_e, float* __restrict__ diag_e, float* __restrict__ extra_e){
    const int bn = blockIdx.x;
    const int b = bn >> 12, n = bn & (Nn - 1);
    const int lane = threadIdx.x;
    float xv[16];
    {
        const float4* xp = (const float4*)(x + (size_t)bn * Ww) + lane * 4;
#pragma unroll
        for (int i = 0; i < 4; ++i){
            float4 v = xp[i];
            xv[4*i+0] = v.x; xv[4*i+1] = v.y; xv[4*i+2] = v.z; xv[4*i+3] = v.w;
        }
    }
#pragma unroll 1
    for (int h = 0; h < Hh; ++h){
        const float4* q1 = (const float4*)(k1 + h * Ww) + lane * 4;
        const float4* q2 = (const float4*)(k2 + h * Ww) + lane * 4;
        const float4* q3 = (const float4*)(k3 + h * Ww) + lane * 4;
        float s1 = 0.f, s2 = 0.f, s3 = 0.f;
#pragma unroll
        for (int i = 0; i < 4; ++i){
            float4 v1 = q1[i], v2 = q2[i], v3 = q3[i];
            s1 += xv[4*i+0]*v1.x + xv[4*i+1]*v1.y + xv[4*i+2]*v1.z + xv[4*i+3]*v1.w;
            s2 += xv[4*i+0]*v2.x + xv[4*i+1]*v2.y + xv[4*i+2]*v2.z + xv[4*i+3]*v2.w;
            s3 += xv[4*i+0]*v3.x + xv[4*i+1]*v3.y + xv[4*i+2]*v3.z + xv[4*i+3]*v3.w;
        }
#pragma unroll
        for (int off = 32; off > 0; off >>= 1){
            s1 += __shfl_down(s1, off);
            s2 += __shfl_down(s2, off);
            s3 += __shfl_down(s3, off);
        }
        if (lane == 0){
            int idx = (b * Hh + h) * Nn + n;
            cross_e[idx] = expf(clamp20(s1 + p1[h * Nn + n]));
            diag_e [idx] = expf(clamp20(s2));
            extra_e[idx] = expf(clamp20(s3));
        }
    }
}

// ---- generic fp32 GEMM: C[M,N] = A[M,K] * B[K,N] -------------------------
#define BM 64
#define BN 64
#define BK 16
__global__ __launch_bounds__(256) void gemm_f32(const float* __restrict__ A,
                                                const float* __restrict__ Bm,
                                                float* __restrict__ C,
                                                int M, int N, int K){
    __shared__ float As[BK][BM];
    __shared__ float Bs[BK][BN];
    const int tid = threadIdx.x;
    const int tx = tid & 15, ty = tid >> 4;
    const int m0 = blockIdx.y * BM, n0 = blockIdx.x * BN;
    float acc[4][4] = {};

    const int ar = tid >> 2;            // A tile row 0..63
    const int ak = (tid & 3) << 2;      // A tile k   0,4,8,12
    const int bk = tid >> 4;            // B tile k   0..15
    const int bn = (tid & 15) << 2;     // B tile col 0,4,..,60

    for (int k0 = 0; k0 < K; k0 += BK){
        float4 av = *(const float4*)(A  + (size_t)(m0 + ar) * K + k0 + ak);
        float4 bv = *(const float4*)(Bm + (size_t)(k0 + bk) * N + n0 + bn);
        As[ak + 0][ar] = av.x;
        As[ak + 1][ar] = av.y;
        As[ak + 2][ar] = av.z;
        As[ak + 3][ar] = av.w;
        *(float4*)&Bs[bk][bn] = bv;
        __syncthreads();
#pragma unroll
        for (int kk = 0; kk < BK; ++kk){
            float4 a4 = *(const float4*)&As[kk][ty * 4];
            float4 b4 = *(const float4*)&Bs[kk][tx * 4];
            float aa[4] = {a4.x, a4.y, a4.z, a4.w};
            float bb[4] = {b4.x, b4.y, b4.z, b4.w};
#pragma unroll
            for (int i = 0; i < 4; ++i)
#pragma unroll
                for (int j = 0; j < 4; ++j)
                    acc[i][j] += aa[i] * bb[j];
        }
        __syncthreads();
    }
#pragma unroll
    for (int i = 0; i < 4; ++i){
        size_t row = (size_t)(m0 + ty * 4 + i) * N + n0 + tx * 4;
#pragma unroll
        for (int j = 0; j < 4; ++j)
            C[row + j] = acc[i][j];
    }
}

// ---- scan pass 1: per-chunk sums ----------------------------------------
__global__ __launch_bounds__(64) void scan1(const float* __restrict__ values,
                                            const float* __restrict__ cross_e,
                                            float* __restrict__ csum_c, float* __restrict__ csum_cv){
    const int blk = blockIdx.x;          // (b*H + h)*J + j
    const int j = blk & (Jj - 1);
    const int bh = blk >> 6;
    const int h = bh & (Hh - 1), b = bh >> 4;
    const int lane = threadIdx.x;
    const float* cp = cross_e + bh * Nn + j * Ll;
    float sc = 0.f, scv = 0.f;
    for (int t = 0; t < Ll; ++t){
        int n = j * Ll + t;
        float ce = cp[t];
        float v = values[((size_t)(b * Nn + n) << 10) + (h << 6) + lane];
        sc += ce;
        scv += ce * v;
    }
    if (lane == 0) csum_c[blk] = sc;
    csum_cv[(blk << 6) + lane] = scv;
}

// ---- scan pass 2: exclusive prefix over chunks ---------------------------
__global__ __launch_bounds__(64) void scan2(const float* __restrict__ csum_c,
                                            const float* __restrict__ csum_cv,
                                            float* __restrict__ pref_c, float* __restrict__ pref_cv){
    const int bh = blockIdx.x;
    const int lane = threadIdx.x;
    float rc = 0.f, rcv = 0.f;
    for (int j = 0; j < Jj; ++j){
        int idx = bh * Jj + j;
        if (lane == 0) pref_c[idx] = rc;
        pref_cv[(idx << 6) + lane] = rcv;
        rc  += csum_c[idx];
        rcv += csum_cv[(idx << 6) + lane];
    }
}

// ---- scan pass 3: apply + pointwise, write out2 [B][N][H][A] -------------
__global__ __launch_bounds__(64) void scan3(const float* __restrict__ values,
                                            const float* __restrict__ cross_e,
                                            const float* __restrict__ diag_e,
                                            const float* __restrict__ extra_e,
                                            const float* __restrict__ p2e,
                                            const float* __restrict__ pref_c,
                                            const float* __restrict__ pref_cv,
                                            float* __restrict__ out2){
    const int blk = blockIdx.x;          // (b*H + h)*J + j
    const int j = blk & (Jj - 1);
    const int bh = blk >> 6;
    const int h = bh & (Hh - 1), b = bh >> 4;
    const int lane = threadIdx.x;
    const float* cp = cross_e + bh * Nn + j * Ll;
    const float* dp = diag_e  + bh * Nn + j * Ll;
    const float* ep = extra_e + bh * Nn + j * Ll;
    const float* pp = p2e + h * Nn + j * Ll;
    float rc  = pref_c[blk];
    float rcv = pref_cv[(blk << 6) + lane];
    for (int t = 0; t < Ll; ++t){
        int n = j * Ll + t;
        float ce = cp[t], de = dp[t], ee = ep[t], pe = pp[t];
        size_t vidx = ((size_t)(b * Nn + n) << 10) + (h << 6) + lane;
        float v = values[vidx];
        rcv += ce * v;
        rc  += ce;
        float pee = pe * ee;
        float num = rcv * pee + v * de;
        float den = rc  * pee + de;
        out2[vidx] = num / den;
    }
}

extern "C" void kernel_launch(void* const* d_in, const int* in_sizes, int n_in,
                              void* d_out, int out_size, void* d_ws, size_t ws_size,
                              hipStream_t stream){
    const float* x  = (const float*)d_in[0];
    const float* k1 = (const float*)d_in[1];
    const float* k2 = (const float*)d_in[2];
    const float* k3 = (const float*)d_in[3];
    const float* a1 = (const float*)d_in[4];
    const float* a2 = (const float*)d_in[5];
    const float* b1 = (const float*)d_in[6];
    const float* b2 = (const float*)d_in[7];
    const float* c  = (const float*)d_in[8];
    const float* vw = (const float*)d_in[9];
    const float* ow = (const float*)d_in[10];
    float* out = (float*)d_out;

    char* p = (char*)d_ws;
    auto alloc = [&](size_t bytes) -> void* {
        void* r = (void*)p;
        p += (bytes + 255) & ~(size_t)255;
        return r;
    };
    float* VW2     = (float*)alloc((size_t)Ww * Hh * Aa * 4);
    float* OW2     = (float*)alloc((size_t)Hh * Aa * Ww * 4);
    float* p1      = (float*)alloc((size_t)Hh * Nn * 4);
    float* p2e     = (float*)alloc((size_t)Hh * Nn * 4);
    float* cross_e = (float*)alloc((size_t)Bb * Hh * Nn * 4);
    float* diag_e  = (float*)alloc((size_t)Bb * Hh * Nn * 4);
    float* extra_e = (float*)alloc((size_t)Bb * Hh * Nn * 4);
    float* csum_c  = (float*)alloc((size_t)Bb * Hh * Jj * 4);
    float* pref_c  = (float*)alloc((size_t)Bb * Hh * Jj * 4);
    float* csum_cv = (float*)alloc((size_t)Bb * Hh * Jj * Aa * 4);
    float* pref_cv = (float*)alloc((size_t)Bb * Hh * Jj * Aa * 4);
    float* values  = (float*)alloc((size_t)Bb * Nn * Hh * Aa * 4);
    float* out2    = (float*)alloc((size_t)Bb * Nn * Hh * Aa * 4);

    t_vw<<<(Hh * Ww * Aa) / 256, 256, 0, stream>>>(vw, VW2);
    t_ow<<<(Hh * Ww * Aa) / 256, 256, 0, stream>>>(ow, OW2);
    p_kernel<<<(Hh * Nn) / 256, 256, 0, stream>>>(a1, a2, b1, b2, c, p1, p2e);
    proj_kernel<<<Bb * Nn, 64, 0, stream>>>(x, k1, k2, k3, p1, cross_e, diag_e, extra_e);
    gemm_f32<<<dim3((Hh * Aa) / BN, (Bb * Nn) / BM), 256, 0, stream>>>(x, VW2, values, Bb * Nn, Hh * Aa, Ww);
    scan1<<<Bb * Hh * Jj, 64, 0, stream>>>(values, cross_e, csum_c, csum_cv);
    scan2<<<Bb * Hh, 64, 0, stream>>>(csum_c, csum_cv, pref_c, pref_cv);
    scan3<<<Bb * Hh * Jj, 64, 0, stream>>>(values, cross_e, diag_e, extra_e, p2e, pref_c, pref_cv, out2);
    gemm_f32<<<dim3(Ww / BN, (Bb * Nn) / BM), 256, 0, stream>>>(out2, OW2, out, Bb * Nn, Ww, Ww);
}

// Round 3
// 418.998 us; speedup vs baseline: 3.0175x; 3.0175x over previous
//
#include <hip/hip_runtime.h>
#include <hip/hip_bf16.h>
#include <stdint.h>

typedef __hip_bfloat16 bf16;
typedef __attribute__((ext_vector_type(8))) short short8;   // 8 bf16 (4 VGPRs)
typedef __attribute__((ext_vector_type(4))) float floatx4;  // 4 fp32 acc

#define Bb 4
#define Nn 4096
#define Ww 1024
#define Hh 16
#define Aa 64
#define Pp 64
#define Jj 64   // scan chunks per (b,h)
#define Ll 64   // chunk length

__device__ __forceinline__ float clamp20(float z){ return fminf(fmaxf(z, -20.0f), 20.0f); }

__device__ __forceinline__ void gl_lds16(const bf16* g, bf16* l){
    __builtin_amdgcn_global_load_lds((const __attribute__((address_space(1))) void*)g,
                                     (__attribute__((address_space(3))) void*)l, 16, 0, 0);
}

// ---- x fp32 -> bf16 ------------------------------------------------------
__global__ __launch_bounds__(256) void cvt_x(const float* __restrict__ in, bf16* __restrict__ o){
    size_t i = ((size_t)blockIdx.x * 256 + threadIdx.x) * 4;
    float4 v = *(const float4*)(in + i);
    bf16 t0 = __float2bfloat16(v.x), t1 = __float2bfloat16(v.y);
    bf16 t2 = __float2bfloat16(v.z), t3 = __float2bfloat16(v.w);
    ushort4 pk = make_ushort4(*(unsigned short*)&t0, *(unsigned short*)&t1,
                              *(unsigned short*)&t2, *(unsigned short*)&t3);
    *(ushort4*)(o + i) = pk;
}

// ---- value_weight [H][W][A] -> VWt [H*A][W] bf16 (Bt layout for GEMM1) ---
__global__ __launch_bounds__(256) void t_vw(const float* __restrict__ vw, bf16* __restrict__ VWt){
    int idx = blockIdx.x * 256 + threadIdx.x;   // r*W + w
    int r = idx >> 10, w = idx & (Ww - 1);
    int h = r >> 6, a = r & (Aa - 1);
    VWt[idx] = __float2bfloat16(vw[(h << 16) + (w << 6) + a]);
}

// ---- output_weight [H][W][A] -> OWt [W][H*A] bf16 (Bt layout for GEMM2) --
__global__ __launch_bounds__(256) void t_ow(const float* __restrict__ ow, bf16* __restrict__ OWt){
    int idx = blockIdx.x * 256 + threadIdx.x;   // w*(H*A) + r
    int w = idx >> 10, r = idx & 1023;
    int h = r >> 6, a = r & (Aa - 1);
    OWt[idx] = __float2bfloat16(ow[(h << 16) + (w << 6) + a]);
}

// ---- p1[h,n] raw, p2e[h,n] = exp(clip(p2)) -------------------------------
__global__ __launch_bounds__(256) void p_kernel(const float* __restrict__ a1, const float* __restrict__ a2,
                                                const float* __restrict__ b1, const float* __restrict__ b2,
                                                const float* __restrict__ c,
                                                float* __restrict__ p1, float* __restrict__ p2e){
    int idx = blockIdx.x * 256 + threadIdx.x;   // h*N + i
    int h = idx >> 12, i = idx & (Nn - 1);
    float t = (float)i * (1.0f / (float)(Nn - 1));
    float s1 = 0.f, s2 = 0.f;
    for (int p = 0; p < Pp; ++p){
        float av1 = a1[h * Pp + p], av2 = a2[h * Pp + p];
        float bv1 = b1[h * Pp + p], bv2 = b2[h * Pp + p];
        float cv  = c [h * Pp + p];
        s1 += sinf(av1 * t + bv1) * cv;
        s2 += sinf(av2 * t + bv2) * cv;
    }
    p1[idx]  = s1;
    p2e[idx] = expf(clamp20(s2));
}

// ---- projections: one wave handles 4 consecutive n (amortize k reads) ----
__global__ __launch_bounds__(64) void proj_kernel(const float* __restrict__ x,
    const float* __restrict__ k1, const float* __restrict__ k2, const float* __restrict__ k3,
    const float* __restrict__ p1,
    float* __restrict__ cross_e, float* __restrict__ diag_e, float* __restrict__ extra_e){
    const int blk = blockIdx.x;                 // Bb*Nn/4 blocks
    const int b = blk >> 10;
    const int n0 = (blk & 1023) * 4;
    const int lane = threadIdx.x;
    float xv[4][16];
#pragma unroll
    for (int q = 0; q < 4; ++q){
        const float4* xp = (const float4*)(x + ((size_t)(b * Nn + n0 + q)) * Ww) + lane * 4;
#pragma unroll
        for (int i = 0; i < 4; ++i){
            float4 v = xp[i];
            xv[q][4*i+0] = v.x; xv[q][4*i+1] = v.y; xv[q][4*i+2] = v.z; xv[q][4*i+3] = v.w;
        }
    }
#pragma unroll 1
    for (int h = 0; h < Hh; ++h){
        float kv[3][16];
        const float4* q1 = (const float4*)(k1 + h * Ww) + lane * 4;
        const float4* q2 = (const float4*)(k2 + h * Ww) + lane * 4;
        const float4* q3 = (const float4*)(k3 + h * Ww) + lane * 4;
#pragma unroll
        for (int i = 0; i < 4; ++i){
            float4 v1 = q1[i], v2 = q2[i], v3 = q3[i];
            kv[0][4*i+0]=v1.x; kv[0][4*i+1]=v1.y; kv[0][4*i+2]=v1.z; kv[0][4*i+3]=v1.w;
            kv[1][4*i+0]=v2.x; kv[1][4*i+1]=v2.y; kv[1][4*i+2]=v2.z; kv[1][4*i+3]=v2.w;
            kv[2][4*i+0]=v3.x; kv[2][4*i+1]=v3.y; kv[2][4*i+2]=v3.z; kv[2][4*i+3]=v3.w;
        }
        float s[12];
#pragma unroll
        for (int m = 0; m < 3; ++m)
#pragma unroll
            for (int q = 0; q < 4; ++q){
                float acc = 0.f;
#pragma unroll
                for (int i = 0; i < 16; ++i) acc += xv[q][i] * kv[m][i];
                s[m * 4 + q] = acc;
            }
#pragma unroll
        for (int t = 0; t < 12; ++t){
            float v = s[t];
#pragma unroll
            for (int off = 32; off > 0; off >>= 1) v += __shfl_down(v, off);
            s[t] = v;
        }
        if (lane == 0){
#pragma unroll
            for (int q = 0; q < 4; ++q){
                int idx = (b * Hh + h) * Nn + n0 + q;
                cross_e[idx] = expf(clamp20(s[0 * 4 + q] + p1[h * Nn + n0 + q]));
                diag_e [idx] = expf(clamp20(s[1 * 4 + q]));
                extra_e[idx] = expf(clamp20(s[2 * 4 + q]));
            }
        }
    }
}

// ---- MFMA GEMM (m97 structure): C[M,N] = A[M,K] * Bt[N,K]^T --------------
// 128x128 tile, BK=32, 4 waves (2x2), 4x4 16x16x32 MFMA tiles per wave.
template<int WRITE_BF16>
__global__ __launch_bounds__(256) void gemm_bt(const bf16* __restrict__ A,
                                               const bf16* __restrict__ Bt,
                                               void* __restrict__ Cv,
                                               int M, int N, int K){
    __shared__ bf16 As[128 * 32];
    __shared__ bf16 Bs[128 * 32];
    const int tid  = threadIdx.x;
    const int wave = tid >> 6, lane = tid & 63;
    const int m0 = blockIdx.y * 128, n0 = blockIdx.x * 128;
    const int wm = (wave & 1) * 64, wn = (wave >> 1) * 64;

    // staging: each wave stages rows [wave*32, wave*32+32) of A and Bt,
    // two 16-row global_load_lds(16B) instructions per matrix.
    const int srow = wave * 32 + (lane >> 2);
    const int scol = (lane & 3) * 8;
    const bf16* Ag = A  + (size_t)(m0 + srow) * K + scol;
    const bf16* Bg = Bt + (size_t)(n0 + srow) * K + scol;
    bf16* Al = As + (wave * 32) * 32;
    bf16* Bl = Bs + (wave * 32) * 32;

    floatx4 acc[4][4] = {};
    const int fr = lane & 15;          // row within 16x16 tile
    const int fk = (lane >> 4) * 8;    // k offset (quad*8)

    for (int k0 = 0; k0 < K; k0 += 32){
        gl_lds16(Ag + k0,                 Al);
        gl_lds16(Ag + k0 + (size_t)16 * K, Al + 16 * 32);
        gl_lds16(Bg + k0,                 Bl);
        gl_lds16(Bg + k0 + (size_t)16 * K, Bl + 16 * 32);
        __syncthreads();
        short8 af[4], bfr[4];
#pragma unroll
        for (int i = 0; i < 4; ++i)
            af[i] = *(const short8*)&As[(wm + i * 16 + fr) * 32 + fk];
#pragma unroll
        for (int j = 0; j < 4; ++j)
            bfr[j] = *(const short8*)&Bs[(wn + j * 16 + fr) * 32 + fk];
#pragma unroll
        for (int i = 0; i < 4; ++i)
#pragma unroll
            for (int j = 0; j < 4; ++j)
                acc[i][j] = __builtin_amdgcn_mfma_f32_16x16x32_bf16(af[i], bfr[j], acc[i][j], 0, 0, 0);
        __syncthreads();
    }

    // C/D layout: col = lane&15, row = (lane>>4)*4 + reg   [m89/m91 verified]
    const int cr = (lane >> 4) * 4;
#pragma unroll
    for (int i = 0; i < 4; ++i)
#pragma unroll
        for (int j = 0; j < 4; ++j){
            int row = m0 + wm + i * 16 + cr;
            int col = n0 + wn + j * 16 + fr;
            if (WRITE_BF16){
                bf16* C = (bf16*)Cv;
#pragma unroll
                for (int r = 0; r < 4; ++r)
                    C[(size_t)(row + r) * N + col] = __float2bfloat16(acc[i][j][r]);
            } else {
                float* C = (float*)Cv;
#pragma unroll
                for (int r = 0; r < 4; ++r)
                    C[(size_t)(row + r) * N + col] = acc[i][j][r];
            }
        }
}

// ---- scan pass 1: per-chunk sums ----------------------------------------
__global__ __launch_bounds__(64) void scan1(const bf16* __restrict__ values,
                                            const float* __restrict__ cross_e,
                                            float* __restrict__ csum_c, float* __restrict__ csum_cv){
    const int blk = blockIdx.x;          // (b*H + h)*J + j
    const int j = blk & (Jj - 1);
    const int bh = blk >> 6;
    const int h = bh & (Hh - 1), b = bh >> 4;
    const int lane = threadIdx.x;
    const float* cp = cross_e + bh * Nn + j * Ll;
    float sc = 0.f, scv = 0.f;
    for (int t = 0; t < Ll; ++t){
        int n = j * Ll + t;
        float ce = cp[t];
        float v = __bfloat162float(values[((size_t)(b * Nn + n) << 10) + (h << 6) + lane]);
        sc += ce;
        scv += ce * v;
    }
    if (lane == 0) csum_c[blk] = sc;
    csum_cv[(blk << 6) + lane] = scv;
}

// ---- scan pass 2: exclusive prefix over chunks ---------------------------
__global__ __launch_bounds__(64) void scan2(const float* __restrict__ csum_c,
                                            const float* __restrict__ csum_cv,
                                            float* __restrict__ pref_c, float* __restrict__ pref_cv){
    const int bh = blockIdx.x;
    const int lane = threadIdx.x;
    float rc = 0.f, rcv = 0.f;
    for (int j = 0; j < Jj; ++j){
        int idx = bh * Jj + j;
        if (lane == 0) pref_c[idx] = rc;
        pref_cv[(idx << 6) + lane] = rcv;
        rc  += csum_c[idx];
        rcv += csum_cv[(idx << 6) + lane];
    }
}

// ---- scan pass 3: apply + pointwise -> out2 bf16 [B][N][H*A] -------------
__global__ __launch_bounds__(64) void scan3(const bf16* __restrict__ values,
                                            const float* __restrict__ cross_e,
                                            const float* __restrict__ diag_e,
                                            const float* __restrict__ extra_e,
                                            const float* __restrict__ p2e,
                                            const float* __restrict__ pref_c,
                                            const float* __restrict__ pref_cv,
                                            bf16* __restrict__ out2){
    const int blk = blockIdx.x;
    const int j = blk & (Jj - 1);
    const int bh = blk >> 6;
    const int h = bh & (Hh - 1), b = bh >> 4;
    const int lane = threadIdx.x;
    const float* cp = cross_e + bh * Nn + j * Ll;
    const float* dp = diag_e  + bh * Nn + j * Ll;
    const float* ep = extra_e + bh * Nn + j * Ll;
    const float* pp = p2e + h * Nn + j * Ll;
    float rc  = pref_c[blk];
    float rcv = pref_cv[(blk << 6) + lane];
    for (int t = 0; t < Ll; ++t){
        int n = j * Ll + t;
        float ce = cp[t], de = dp[t], ee = ep[t], pe = pp[t];
        size_t vidx = ((size_t)(b * Nn + n) << 10) + (h << 6) + lane;
        float v = __bfloat162float(values[vidx]);
        rcv += ce * v;
        rc  += ce;
        float pee = pe * ee;
        float num = rcv * pee + v * de;
        float den = rc  * pee + de;
        out2[vidx] = __float2bfloat16(num / den);
    }
}

extern "C" void kernel_launch(void* const* d_in, const int* in_sizes, int n_in,
                              void* d_out, int out_size, void* d_ws, size_t ws_size,
                              hipStream_t stream){
    const float* x  = (const float*)d_in[0];
    const float* k1 = (const float*)d_in[1];
    const float* k2 = (const float*)d_in[2];
    const float* k3 = (const float*)d_in[3];
    const float* a1 = (const float*)d_in[4];
    const float* a2 = (const float*)d_in[5];
    const float* b1 = (const float*)d_in[6];
    const float* b2 = (const float*)d_in[7];
    const float* c  = (const float*)d_in[8];
    const float* vw = (const float*)d_in[9];
    const float* ow = (const float*)d_in[10];
    float* out = (float*)d_out;

    char* p = (char*)d_ws;
    auto alloc = [&](size_t bytes) -> void* {
        void* r = (void*)p;
        p += (bytes + 255) & ~(size_t)255;
        return r;
    };
    bf16*  xb      = (bf16*) alloc((size_t)Bb * Nn * Ww * 2);
    bf16*  VWt     = (bf16*) alloc((size_t)Hh * Aa * Ww * 2);
    bf16*  OWt     = (bf16*) alloc((size_t)Ww * Hh * Aa * 2);
    float* p1      = (float*)alloc((size_t)Hh * Nn * 4);
    float* p2e     = (float*)alloc((size_t)Hh * Nn * 4);
    float* cross_e = (float*)alloc((size_t)Bb * Hh * Nn * 4);
    float* diag_e  = (float*)alloc((size_t)Bb * Hh * Nn * 4);
    float* extra_e = (float*)alloc((size_t)Bb * Hh * Nn * 4);
    float* csum_c  = (float*)alloc((size_t)Bb * Hh * Jj * 4);
    float* pref_c  = (float*)alloc((size_t)Bb * Hh * Jj * 4);
    float* csum_cv = (float*)alloc((size_t)Bb * Hh * Jj * Aa * 4);
    float* pref_cv = (float*)alloc((size_t)Bb * Hh * Jj * Aa * 4);
    bf16*  values  = (bf16*) alloc((size_t)Bb * Nn * Hh * Aa * 2);
    bf16*  out2    = (bf16*) alloc((size_t)Bb * Nn * Hh * Aa * 2);

    cvt_x<<<(Bb * Nn * Ww) / (256 * 4), 256, 0, stream>>>(x, xb);
    t_vw<<<(Hh * Aa * Ww) / 256, 256, 0, stream>>>(vw, VWt);
    t_ow<<<(Hh * Aa * Ww) / 256, 256, 0, stream>>>(ow, OWt);
    p_kernel<<<(Hh * Nn) / 256, 256, 0, stream>>>(a1, a2, b1, b2, c, p1, p2e);
    proj_kernel<<<(Bb * Nn) / 4, 64, 0, stream>>>(x, k1, k2, k3, p1, cross_e, diag_e, extra_e);
    gemm_bt<1><<<dim3((Hh * Aa) / 128, (Bb * Nn) / 128), 256, 0, stream>>>(xb, VWt, (void*)values, Bb * Nn, Hh * Aa, Ww);
    scan1<<<Bb * Hh * Jj, 64, 0, stream>>>(values, cross_e, csum_c, csum_cv);
    scan2<<<Bb * Hh, 64, 0, stream>>>(csum_c, csum_cv, pref_c, pref_cv);
    scan3<<<Bb * Hh * Jj, 64, 0, stream>>>(values, cross_e, diag_e, extra_e, p2e, pref_c, pref_cv, out2);
    gemm_bt<0><<<dim3(Ww / 128, (Bb * Nn) / 128), 256, 0, stream>>>(out2, OWt, (void*)out, Bb * Nn, Ww, Hh * Aa);
}

// Round 4
// 348.620 us; speedup vs baseline: 3.6267x; 1.2019x over previous
//
#include <hip/hip_runtime.h>
#include <hip/hip_bf16.h>
#include <stdint.h>

typedef __hip_bfloat16 bf16;
typedef __attribute__((ext_vector_type(8))) short short8;   // 8 bf16 (4 VGPRs)
typedef __attribute__((ext_vector_type(4))) float floatx4;  // 4 fp32 acc

#define Bb 4
#define Nn 4096
#define Ww 1024
#define Hh 16
#define Aa 64
#define Pp 64
#define Jj 64   // scan chunks per (b,h)
#define Ll 64   // chunk length

__device__ __forceinline__ float clamp20(float z){ return fminf(fmaxf(z, -20.0f), 20.0f); }

__device__ __forceinline__ void gl_lds16(const bf16* g, bf16* l){
    __builtin_amdgcn_global_load_lds((const __attribute__((address_space(1))) void*)g,
                                     (__attribute__((address_space(3))) void*)l, 16, 0, 0);
}

// ---- x fp32 -> bf16 ------------------------------------------------------
__global__ __launch_bounds__(256) void cvt_x(const float* __restrict__ in, bf16* __restrict__ o){
    size_t i = ((size_t)blockIdx.x * 256 + threadIdx.x) * 4;
    float4 v = *(const float4*)(in + i);
    bf16 t0 = __float2bfloat16(v.x), t1 = __float2bfloat16(v.y);
    bf16 t2 = __float2bfloat16(v.z), t3 = __float2bfloat16(v.w);
    ushort4 pk = make_ushort4(*(unsigned short*)&t0, *(unsigned short*)&t1,
                              *(unsigned short*)&t2, *(unsigned short*)&t3);
    *(ushort4*)(o + i) = pk;
}

// ---- k1,k2,k3 [16][1024] fp32 -> Ktp [64][1024] bf16 (rows 48-63 zero) ---
__global__ __launch_bounds__(256) void t_k(const float* __restrict__ k1, const float* __restrict__ k2,
                                           const float* __restrict__ k3, bf16* __restrict__ Ktp){
    int idx = blockIdx.x * 256 + threadIdx.x;   // r*1024 + k, 64*1024 total
    int r = idx >> 10, k = idx & 1023;
    float v = 0.f;
    if (r < 16)      v = k1[r * 1024 + k];
    else if (r < 32) v = k2[(r - 16) * 1024 + k];
    else if (r < 48) v = k3[(r - 32) * 1024 + k];
    Ktp[idx] = __float2bfloat16(v);
}

// ---- value_weight [H][W][A] -> VWt [H*A][W] bf16 (Bt layout for GEMM1) ---
__global__ __launch_bounds__(256) void t_vw(const float* __restrict__ vw, bf16* __restrict__ VWt){
    int idx = blockIdx.x * 256 + threadIdx.x;   // r*W + w
    int r = idx >> 10, w = idx & (Ww - 1);
    int h = r >> 6, a = r & (Aa - 1);
    VWt[idx] = __float2bfloat16(vw[(h << 16) + (w << 6) + a]);
}

// ---- output_weight [H][W][A] -> OWt [W][H*A] bf16 (Bt layout for GEMM2) --
__global__ __launch_bounds__(256) void t_ow(const float* __restrict__ ow, bf16* __restrict__ OWt){
    int idx = blockIdx.x * 256 + threadIdx.x;   // w*(H*A) + r
    int w = idx >> 10, r = idx & 1023;
    int h = r >> 6, a = r & (Aa - 1);
    OWt[idx] = __float2bfloat16(ow[(h << 16) + (w << 6) + a]);
}

// ---- p1[h,n] raw, p2e[h,n] = exp(clip(p2)) -------------------------------
__global__ __launch_bounds__(256) void p_kernel(const float* __restrict__ a1, const float* __restrict__ a2,
                                                const float* __restrict__ b1, const float* __restrict__ b2,
                                                const float* __restrict__ c,
                                                float* __restrict__ p1, float* __restrict__ p2e){
    int idx = blockIdx.x * 256 + threadIdx.x;   // h*N + i
    int h = idx >> 12, i = idx & (Nn - 1);
    float t = (float)i * (1.0f / (float)(Nn - 1));
    float s1 = 0.f, s2 = 0.f;
    for (int p = 0; p < Pp; ++p){
        float av1 = a1[h * Pp + p], av2 = a2[h * Pp + p];
        float bv1 = b1[h * Pp + p], bv2 = b2[h * Pp + p];
        float cv  = c [h * Pp + p];
        s1 += __sinf(av1 * t + bv1) * cv;   // |arg| <= 0.1 -> HW sin is exact enough
        s2 += __sinf(av2 * t + bv2) * cv;
    }
    p1[idx]  = s1;
    p2e[idx] = expf(clamp20(s2));
}

// ---- projection GEMM: S[16384,48] = xb * Ktp^T, epilogue exp+scatter -----
// 256-row x 64-col tile, 4 waves (64 rows each), 4x3 MFMA tiles (j=3 is pad).
__global__ __launch_bounds__(256) void proj_gemm(const bf16* __restrict__ A,
                                                 const bf16* __restrict__ Ktp,
                                                 const float* __restrict__ p1,
                                                 float* __restrict__ cross_e,
                                                 float* __restrict__ diag_e,
                                                 float* __restrict__ extra_e){
    __shared__ bf16 As[256 * 32];
    __shared__ bf16 Bs[64 * 32];
    const int tid  = threadIdx.x;
    const int wave = tid >> 6, lane = tid & 63;
    const int m0 = blockIdx.x * 256;

    const int lrow = lane >> 2;            // 0..15
    const int scol = (lane & 3) * 8;       // 0,8,16,24
    const bf16* Bg = Ktp + (size_t)(wave * 16 + lrow) * 1024 + scol;
    bf16* Bl = Bs + (wave * 16) * 32;

    floatx4 acc[4][3] = {};
    const int fr = lane & 15;              // tile row / col-in-tile
    const int fk = (lane >> 4) * 8;        // k offset (quad*8)

    for (int k0 = 0; k0 < 1024; k0 += 32){
#pragma unroll
        for (int q = 0; q < 4; ++q){
            int srow = wave * 64 + q * 16 + lrow;
            gl_lds16(A + (size_t)(m0 + srow) * 1024 + k0 + scol, As + (wave * 64 + q * 16) * 32);
        }
        gl_lds16(Bg + k0, Bl);
        __syncthreads();
        short8 af[4], bfr[3];
#pragma unroll
        for (int i = 0; i < 4; ++i)
            af[i] = *(const short8*)&As[(wave * 64 + i * 16 + fr) * 32 + fk];
#pragma unroll
        for (int j = 0; j < 3; ++j)
            bfr[j] = *(const short8*)&Bs[(j * 16 + fr) * 32 + fk];
#pragma unroll
        for (int i = 0; i < 4; ++i)
#pragma unroll
            for (int j = 0; j < 3; ++j)
                acc[i][j] = __builtin_amdgcn_mfma_f32_16x16x32_bf16(af[i], bfr[j], acc[i][j], 0, 0, 0);
        __syncthreads();
    }

    // C/D: col = j*16 + (lane&15) -> matrix j, head fr; row = (lane>>4)*4 + reg
    const int cr = (lane >> 4) * 4;
#pragma unroll
    for (int i = 0; i < 4; ++i){
#pragma unroll
        for (int j = 0; j < 3; ++j){
            float* dst = (j == 0) ? cross_e : (j == 1) ? diag_e : extra_e;
#pragma unroll
            for (int r = 0; r < 4; ++r){
                int row = m0 + wave * 64 + i * 16 + cr + r;   // global (b*Nn+n)
                int n = row & (Nn - 1), b = row >> 12;
                float s = acc[i][j][r];
                if (j == 0) s += p1[fr * Nn + n];
                dst[(b * Hh + fr) * Nn + n] = expf(clamp20(s));
            }
        }
    }
}

// ---- MFMA GEMM (m97 structure): C[M,N] = A[M,K] * Bt[N,K]^T --------------
template<int WRITE_BF16>
__global__ __launch_bounds__(256) void gemm_bt(const bf16* __restrict__ A,
                                               const bf16* __restrict__ Bt,
                                               void* __restrict__ Cv,
                                               int M, int N, int K){
    __shared__ bf16 As[128 * 32];
    __shared__ bf16 Bs[128 * 32];
    const int tid  = threadIdx.x;
    const int wave = tid >> 6, lane = tid & 63;
    const int m0 = blockIdx.y * 128, n0 = blockIdx.x * 128;
    const int wm = (wave & 1) * 64, wn = (wave >> 1) * 64;

    const int srow = wave * 32 + (lane >> 2);
    const int scol = (lane & 3) * 8;
    const bf16* Ag = A  + (size_t)(m0 + srow) * K + scol;
    const bf16* Bg = Bt + (size_t)(n0 + srow) * K + scol;
    bf16* Al = As + (wave * 32) * 32;
    bf16* Bl = Bs + (wave * 32) * 32;

    floatx4 acc[4][4] = {};
    const int fr = lane & 15;
    const int fk = (lane >> 4) * 8;

    for (int k0 = 0; k0 < K; k0 += 32){
        gl_lds16(Ag + k0,                  Al);
        gl_lds16(Ag + k0 + (size_t)16 * K, Al + 16 * 32);
        gl_lds16(Bg + k0,                  Bl);
        gl_lds16(Bg + k0 + (size_t)16 * K, Bl + 16 * 32);
        __syncthreads();
        short8 af[4], bfr[4];
#pragma unroll
        for (int i = 0; i < 4; ++i)
            af[i] = *(const short8*)&As[(wm + i * 16 + fr) * 32 + fk];
#pragma unroll
        for (int j = 0; j < 4; ++j)
            bfr[j] = *(const short8*)&Bs[(wn + j * 16 + fr) * 32 + fk];
#pragma unroll
        for (int i = 0; i < 4; ++i)
#pragma unroll
            for (int j = 0; j < 4; ++j)
                acc[i][j] = __builtin_amdgcn_mfma_f32_16x16x32_bf16(af[i], bfr[j], acc[i][j], 0, 0, 0);
        __syncthreads();
    }

    const int cr = (lane >> 4) * 4;
#pragma unroll
    for (int i = 0; i < 4; ++i)
#pragma unroll
        for (int j = 0; j < 4; ++j){
            int row = m0 + wm + i * 16 + cr;
            int col = n0 + wn + j * 16 + fr;
            if (WRITE_BF16){
                bf16* C = (bf16*)Cv;
#pragma unroll
                for (int r = 0; r < 4; ++r)
                    C[(size_t)(row + r) * N + col] = __float2bfloat16(acc[i][j][r]);
            } else {
                float* C = (float*)Cv;
#pragma unroll
                for (int r = 0; r < 4; ++r)
                    C[(size_t)(row + r) * N + col] = acc[i][j][r];
            }
        }
}

// ---- scan pass 1: per-chunk sums ----------------------------------------
__global__ __launch_bounds__(64) void scan1(const bf16* __restrict__ values,
                                            const float* __restrict__ cross_e,
                                            float* __restrict__ csum_c, float* __restrict__ csum_cv){
    const int blk = blockIdx.x;          // (b*H + h)*J + j
    const int j = blk & (Jj - 1);
    const int bh = blk >> 6;
    const int h = bh & (Hh - 1), b = bh >> 4;
    const int lane = threadIdx.x;
    const float* cp = cross_e + bh * Nn + j * Ll;
    float sc = 0.f, scv = 0.f;
    for (int t = 0; t < Ll; ++t){
        int n = j * Ll + t;
        float ce = cp[t];
        float v = __bfloat162float(values[((size_t)(b * Nn + n) << 10) + (h << 6) + lane]);
        sc += ce;
        scv += ce * v;
    }
    if (lane == 0) csum_c[blk] = sc;
    csum_cv[(blk << 6) + lane] = scv;
}

// ---- scan pass 2: exclusive prefix over chunks ---------------------------
__global__ __launch_bounds__(64) void scan2(const float* __restrict__ csum_c,
                                            const float* __restrict__ csum_cv,
                                            float* __restrict__ pref_c, float* __restrict__ pref_cv){
    const int bh = blockIdx.x;
    const int lane = threadIdx.x;
    float rc = 0.f, rcv = 0.f;
    for (int j = 0; j < Jj; ++j){
        int idx = bh * Jj + j;
        if (lane == 0) pref_c[idx] = rc;
        pref_cv[(idx << 6) + lane] = rcv;
        rc  += csum_c[idx];
        rcv += csum_cv[(idx << 6) + lane];
    }
}

// ---- scan pass 3: apply + pointwise -> out2 bf16 [B][N][H*A] -------------
__global__ __launch_bounds__(64) void scan3(const bf16* __restrict__ values,
                                            const float* __restrict__ cross_e,
                                            const float* __restrict__ diag_e,
                                            const float* __restrict__ extra_e,
                                            const float* __restrict__ p2e,
                                            const float* __restrict__ pref_c,
                                            const float* __restrict__ pref_cv,
                                            bf16* __restrict__ out2){
    const int blk = blockIdx.x;
    const int j = blk & (Jj - 1);
    const int bh = blk >> 6;
    const int h = bh & (Hh - 1), b = bh >> 4;
    const int lane = threadIdx.x;
    const float* cp = cross_e + bh * Nn + j * Ll;
    const float* dp = diag_e  + bh * Nn + j * Ll;
    const float* ep = extra_e + bh * Nn + j * Ll;
    const float* pp = p2e + h * Nn + j * Ll;
    float rc  = pref_c[blk];
    float rcv = pref_cv[(blk << 6) + lane];
    for (int t = 0; t < Ll; ++t){
        int n = j * Ll + t;
        float ce = cp[t], de = dp[t], ee = ep[t], pe = pp[t];
        size_t vidx = ((size_t)(b * Nn + n) << 10) + (h << 6) + lane;
        float v = __bfloat162float(values[vidx]);
        rcv += ce * v;
        rc  += ce;
        float pee = pe * ee;
        float num = rcv * pee + v * de;
        float den = rc  * pee + de;
        out2[vidx] = __float2bfloat16(num / den);
    }
}

extern "C" void kernel_launch(void* const* d_in, const int* in_sizes, int n_in,
                              void* d_out, int out_size, void* d_ws, size_t ws_size,
                              hipStream_t stream){
    const float* x  = (const float*)d_in[0];
    const float* k1 = (const float*)d_in[1];
    const float* k2 = (const float*)d_in[2];
    const float* k3 = (const float*)d_in[3];
    const float* a1 = (const float*)d_in[4];
    const float* a2 = (const float*)d_in[5];
    const float* b1 = (const float*)d_in[6];
    const float* b2 = (const float*)d_in[7];
    const float* c  = (const float*)d_in[8];
    const float* vw = (const float*)d_in[9];
    const float* ow = (const float*)d_in[10];
    float* out = (float*)d_out;

    char* p = (char*)d_ws;
    auto alloc = [&](size_t bytes) -> void* {
        void* r = (void*)p;
        p += (bytes + 255) & ~(size_t)255;
        return r;
    };
    bf16*  xb      = (bf16*) alloc((size_t)Bb * Nn * Ww * 2);
    bf16*  Ktp     = (bf16*) alloc((size_t)64 * Ww * 2);
    bf16*  VWt     = (bf16*) alloc((size_t)Hh * Aa * Ww * 2);
    bf16*  OWt     = (bf16*) alloc((size_t)Ww * Hh * Aa * 2);
    float* p1      = (float*)alloc((size_t)Hh * Nn * 4);
    float* p2e     = (float*)alloc((size_t)Hh * Nn * 4);
    float* cross_e = (float*)alloc((size_t)Bb * Hh * Nn * 4);
    float* diag_e  = (float*)alloc((size_t)Bb * Hh * Nn * 4);
    float* extra_e = (float*)alloc((size_t)Bb * Hh * Nn * 4);
    float* csum_c  = (float*)alloc((size_t)Bb * Hh * Jj * 4);
    float* pref_c  = (float*)alloc((size_t)Bb * Hh * Jj * 4);
    float* csum_cv = (float*)alloc((size_t)Bb * Hh * Jj * Aa * 4);
    float* pref_cv = (float*)alloc((size_t)Bb * Hh * Jj * Aa * 4);
    bf16*  values  = (bf16*) alloc((size_t)Bb * Nn * Hh * Aa * 2);
    bf16*  out2    = (bf16*) alloc((size_t)Bb * Nn * Hh * Aa * 2);

    cvt_x<<<(Bb * Nn * Ww) / (256 * 4), 256, 0, stream>>>(x, xb);
    t_k<<<(64 * Ww) / 256, 256, 0, stream>>>(k1, k2, k3, Ktp);
    t_vw<<<(Hh * Aa * Ww) / 256, 256, 0, stream>>>(vw, VWt);
    t_ow<<<(Hh * Aa * Ww) / 256, 256, 0, stream>>>(ow, OWt);
    p_kernel<<<(Hh * Nn) / 256, 256, 0, stream>>>(a1, a2, b1, b2, c, p1, p2e);
    proj_gemm<<<(Bb * Nn) / 256, 256, 0, stream>>>(xb, Ktp, p1, cross_e, diag_e, extra_e);
    gemm_bt<1><<<dim3((Hh * Aa) / 128, (Bb * Nn) / 128), 256, 0, stream>>>(xb, VWt, (void*)values, Bb * Nn, Hh * Aa, Ww);
    scan1<<<Bb * Hh * Jj, 64, 0, stream>>>(values, cross_e, csum_c, csum_cv);
    scan2<<<Bb * Hh, 64, 0, stream>>>(csum_c, csum_cv, pref_c, pref_cv);
    scan3<<<Bb * Hh * Jj, 64, 0, stream>>>(values, cross_e, diag_e, extra_e, p2e, pref_c, pref_cv, out2);
    gemm_bt<0><<<dim3(Ww / 128, (Bb * Nn) / 128), 256, 0, stream>>>(out2, OWt, (void*)out, Bb * Nn, Ww, Hh * Aa);
}